// Round 2
// baseline (195.220 us; speedup 1.0000x reference)
//
#include <hip/hip_runtime.h>
#include <stdint.h>

#define BATCH 64
#define NPS (512*512)                      // 262144 elements per sample
#define TOTELEM ((double)BATCH*(double)NPS)
#define THREADS 256
#define BLK_PER_SAMPLE 32
#define NBLOCKS (BATCH*BLK_PER_SAMPLE)     // 2048 = 8 blocks/CU on 256 CUs
#define ELEMS_PER_BLOCK (NPS/BLK_PER_SAMPLE) // 8192
#define V4_PER_THREAD (ELEMS_PER_BLOCK/(THREADS*4)) // 8
#define HIST_BYTES (BATCH*2048*sizeof(uint32_t))    // 512 KiB, reused H1/H2/H3

struct Scal {
  float bce, psum, tsum, inter;
  uint32_t ones[BATCH];
  float Stot[BATCH];
  float Slow[BATCH];   // sigmoid-sum strictly below current refinement bin
  float Ssm[BATCH];    // final S_small
  int b1[BATCH]; uint32_t r1[BATCH];
  int b2[BATCH]; uint32_t r2[BATCH];
  int mode[BATCH];     // 0 normal, 1 z==0, 2 z==N
};

__device__ __forceinline__ uint32_t f2key(float x){
  uint32_t u = __float_as_uint(x);
  return (u & 0x80000000u) ? ~u : (u | 0x80000000u);
}
__device__ __forceinline__ float key2f(uint32_t k){
  uint32_t u = (k & 0x80000000u) ? (k & 0x7fffffffu) : ~k;
  return __uint_as_float(u);
}
__device__ __forceinline__ float sigmoidf_fast(float x){
  float e = __expf(-fabsf(x));
  float r = 1.0f/(1.0f+e);
  return (x >= 0.0f) ? r : 1.0f - r;
}

// ---------------- pass 1: BCE/Dice sums + per-sample ones + coarse hist ----
__global__ __launch_bounds__(THREADS) void k_pass1(
    const float* __restrict__ x, const float* __restrict__ t,
    uint32_t* __restrict__ H1, Scal* __restrict__ sc)
{
  int s = blockIdx.x / BLK_PER_SAMPLE;
  int chunk = blockIdx.x % BLK_PER_SAMPLE;
  __shared__ uint32_t hist[2048];
  for (int i = threadIdx.x; i < 2048; i += THREADS) hist[i] = 0;
  __syncthreads();
  size_t base = (size_t)s*NPS + (size_t)chunk*ELEMS_PER_BLOCK;
  const float4* x4 = (const float4*)(x + base);
  const float4* t4 = (const float4*)(t + base);
  float bce=0.f, ps=0.f, ts=0.f, inter=0.f; uint32_t on=0;
  #pragma unroll
  for (int it=0; it<V4_PER_THREAD; ++it){
    float4 xv = x4[it*THREADS + threadIdx.x];
    float4 tv = t4[it*THREADS + threadIdx.x];
    float xs[4] = {xv.x, xv.y, xv.z, xv.w};
    float tt4[4] = {tv.x, tv.y, tv.z, tv.w};
    #pragma unroll
    for (int j=0;j<4;j++){
      float xx = xs[j], tt = tt4[j];
      float e = __expf(-fabsf(xx));
      bce += fmaxf(xx,0.f) - xx*tt + __logf(1.f+e);
      float r = 1.f/(1.f+e);
      float p = (xx>=0.f) ? r : 1.f-r;
      ps += p; inter += p*tt; ts += tt; on += (tt>0.5f)?1u:0u;
      atomicAdd(&hist[f2key(xx)>>21], 1u);
    }
  }
  #pragma unroll
  for (int o=32;o>0;o>>=1){
    bce += __shfl_down(bce,o); ps += __shfl_down(ps,o);
    ts  += __shfl_down(ts,o);  inter += __shfl_down(inter,o);
    on  += __shfl_down(on,o);
  }
  __shared__ float rb[4], rp[4], rt[4], ri[4]; __shared__ uint32_t ro[4];
  int wave = threadIdx.x >> 6, lane = threadIdx.x & 63;
  if (lane==0){ rb[wave]=bce; rp[wave]=ps; rt[wave]=ts; ri[wave]=inter; ro[wave]=on; }
  __syncthreads();
  if (threadIdx.x==0){
    float b_=0,p_=0,t_=0,i_=0; uint32_t o_=0;
    for(int w=0;w<4;w++){ b_+=rb[w]; p_+=rp[w]; t_+=rt[w]; i_+=ri[w]; o_+=ro[w]; }
    atomicAdd(&sc->bce,b_); atomicAdd(&sc->psum,p_);
    atomicAdd(&sc->tsum,t_); atomicAdd(&sc->inter,i_);
    atomicAdd(&sc->ones[s], o_); atomicAdd(&sc->Stot[s], p_);
  }
  __syncthreads();
  for (int i = threadIdx.x; i < 2048; i += THREADS){
    uint32_t v = hist[i];
    if (v) atomicAdd(&H1[s*2048+i], v);
  }
}

// ---------------- scan 1: pick coarse bin, zero hist for pass2 -----------
__global__ __launch_bounds__(THREADS) void k_scan1(uint32_t* __restrict__ H, Scal* __restrict__ sc){
  int s = blockIdx.x;
  uint32_t z = (uint32_t)NPS - sc->ones[s];
  if (z==0u){ if(threadIdx.x==0) sc->mode[s]=1; return; }
  if (z==(uint32_t)NPS){ if(threadIdx.x==0) sc->mode[s]=2; return; }
  if (threadIdx.x==0) sc->mode[s]=0;
  __shared__ uint32_t h[2048]; __shared__ uint32_t pre[THREADS];
  for (int i=threadIdx.x;i<2048;i+=THREADS) h[i]=H[s*2048+i];
  __syncthreads();
  for (int i=threadIdx.x;i<2048;i+=THREADS) H[s*2048+i]=0;   // ready for pass2
  uint32_t local=0;
  #pragma unroll
  for(int j=0;j<8;j++) local += h[threadIdx.x*8+j];
  pre[threadIdx.x]=local;
  __syncthreads();
  if (threadIdx.x==0){ uint32_t c=0; for(int i=0;i<THREADS;i++){uint32_t v=pre[i]; pre[i]=c; c+=v;} }
  __syncthreads();
  uint32_t before = pre[threadIdx.x];
  if (before < z && z <= before+local){
    uint32_t c=before;
    for(int j=0;j<8;j++){
      uint32_t hv=h[threadIdx.x*8+j];
      if (z <= c+hv){ sc->b1[s]=threadIdx.x*8+j; sc->r1[s]=z-c; break; }
      c+=hv;
    }
  }
}

// ---------------- pass 2: sigmoid-sum below b1 + mid hist ----------------
__global__ __launch_bounds__(THREADS) void k_pass2(
    const float* __restrict__ x, uint32_t* __restrict__ H2, Scal* __restrict__ sc)
{
  int s = blockIdx.x / BLK_PER_SAMPLE;
  if (sc->mode[s] != 0) return;
  int bb = sc->b1[s];
  int chunk = blockIdx.x % BLK_PER_SAMPLE;
  __shared__ uint32_t hist[2048];
  for (int i=threadIdx.x;i<2048;i+=THREADS) hist[i]=0;
  __syncthreads();
  size_t base = (size_t)s*NPS + (size_t)chunk*ELEMS_PER_BLOCK;
  const float4* x4 = (const float4*)(x + base);
  float sl = 0.f;
  #pragma unroll
  for (int it=0; it<V4_PER_THREAD; ++it){
    float4 xv = x4[it*THREADS + threadIdx.x];
    float xs[4] = {xv.x, xv.y, xv.z, xv.w};
    #pragma unroll
    for (int j=0;j<4;j++){
      float xx = xs[j];
      uint32_t k = f2key(xx);
      int hi = (int)(k>>21);
      if (hi < bb) sl += sigmoidf_fast(xx);
      else if (hi == bb) atomicAdd(&hist[(k>>10)&0x7FFu], 1u);
    }
  }
  #pragma unroll
  for (int o=32;o>0;o>>=1) sl += __shfl_down(sl,o);
  __shared__ float rs[4];
  int wave=threadIdx.x>>6, lane=threadIdx.x&63;
  if(lane==0) rs[wave]=sl;
  __syncthreads();
  if(threadIdx.x==0) atomicAdd(&sc->Slow[s], rs[0]+rs[1]+rs[2]+rs[3]);
  __syncthreads();
  for (int i=threadIdx.x;i<2048;i+=THREADS){ uint32_t v=hist[i]; if(v) atomicAdd(&H2[s*2048+i],v); }
}

// ---------------- scan 2: pick mid bin, zero hist for pass3 --------------
__global__ __launch_bounds__(THREADS) void k_scan2(uint32_t* __restrict__ H, Scal* __restrict__ sc){
  int s = blockIdx.x;
  if (sc->mode[s]!=0) return;
  uint32_t z = sc->r1[s];
  __shared__ uint32_t h[2048]; __shared__ uint32_t pre[THREADS];
  for (int i=threadIdx.x;i<2048;i+=THREADS) h[i]=H[s*2048+i];
  __syncthreads();
  for (int i=threadIdx.x;i<2048;i+=THREADS) H[s*2048+i]=0;   // ready for pass3
  uint32_t local=0;
  #pragma unroll
  for(int j=0;j<8;j++) local += h[threadIdx.x*8+j];
  pre[threadIdx.x]=local;
  __syncthreads();
  if (threadIdx.x==0){ uint32_t c=0; for(int i=0;i<THREADS;i++){uint32_t v=pre[i]; pre[i]=c; c+=v;} }
  __syncthreads();
  uint32_t before = pre[threadIdx.x];
  if (before < z && z <= before+local){
    uint32_t c=before;
    for(int j=0;j<8;j++){
      uint32_t hv=h[threadIdx.x*8+j];
      if (z <= c+hv){ sc->b2[s]=threadIdx.x*8+j; sc->r2[s]=z-c; break; }
      c+=hv;
    }
  }
}

// ---------------- pass 3: sigmoid-sum below b2 within b1 + exact-key hist -
__global__ __launch_bounds__(THREADS) void k_pass3(
    const float* __restrict__ x, uint32_t* __restrict__ H3, Scal* __restrict__ sc)
{
  int s = blockIdx.x / BLK_PER_SAMPLE;
  if (sc->mode[s] != 0) return;
  int bb = sc->b1[s];
  int b2 = sc->b2[s];
  int chunk = blockIdx.x % BLK_PER_SAMPLE;
  __shared__ uint32_t hist[1024];
  for (int i=threadIdx.x;i<1024;i+=THREADS) hist[i]=0;
  __syncthreads();
  size_t base = (size_t)s*NPS + (size_t)chunk*ELEMS_PER_BLOCK;
  const float4* x4 = (const float4*)(x + base);
  float sl = 0.f;
  #pragma unroll
  for (int it=0; it<V4_PER_THREAD; ++it){
    float4 xv = x4[it*THREADS + threadIdx.x];
    float xs[4] = {xv.x, xv.y, xv.z, xv.w};
    #pragma unroll
    for (int j=0;j<4;j++){
      float xx = xs[j];
      uint32_t k = f2key(xx);
      int hi = (int)(k>>21);
      if (hi == bb){
        int mid = (int)((k>>10)&0x7FFu);
        if (mid < b2) sl += sigmoidf_fast(xx);
        else if (mid == b2) atomicAdd(&hist[k & 0x3FFu], 1u);
      }
    }
  }
  #pragma unroll
  for (int o=32;o>0;o>>=1) sl += __shfl_down(sl,o);
  __shared__ float rs[4];
  int wave=threadIdx.x>>6, lane=threadIdx.x&63;
  if(lane==0) rs[wave]=sl;
  __syncthreads();
  if(threadIdx.x==0) atomicAdd(&sc->Slow[s], rs[0]+rs[1]+rs[2]+rs[3]);
  __syncthreads();
  for (int i=threadIdx.x;i<1024;i+=THREADS){ uint32_t v=hist[i]; if(v) atomicAdd(&H3[s*1024+i],v); }
}

// ---------------- scan 3: exact key + close S_small ----------------------
__global__ __launch_bounds__(THREADS) void k_scan3(const uint32_t* __restrict__ H3, Scal* __restrict__ sc){
  int s = blockIdx.x;
  int m = sc->mode[s];
  if (m){ if(threadIdx.x==0) sc->Ssm[s] = (m==1) ? 0.f : sc->Stot[s]; return; }
  __shared__ uint32_t h[1024]; __shared__ uint32_t pre[THREADS];
  __shared__ int sb3; __shared__ uint32_t sr3;
  for (int i=threadIdx.x;i<1024;i+=THREADS) h[i]=H3[s*1024+i];
  __syncthreads();
  uint32_t z = sc->r2[s];
  uint32_t local=0;
  #pragma unroll
  for(int j=0;j<4;j++) local += h[threadIdx.x*4+j];
  pre[threadIdx.x]=local;
  __syncthreads();
  if (threadIdx.x==0){ uint32_t c=0; for(int i=0;i<THREADS;i++){uint32_t v=pre[i]; pre[i]=c; c+=v;} }
  __syncthreads();
  uint32_t before=pre[threadIdx.x];
  if (before<z && z<=before+local){
    uint32_t c=before;
    for(int j=0;j<4;j++){
      uint32_t hv=h[threadIdx.x*4+j];
      if(z<=c+hv){ sb3=threadIdx.x*4+j; sr3=z-c; break; }
      c+=hv;
    }
  }
  __syncthreads();
  int b3 = sb3; uint32_t r3 = sr3;
  uint32_t keybase = ((uint32_t)sc->b1[s]<<21) | ((uint32_t)sc->b2[s]<<10);
  float acc=0.f;
  for (int j=threadIdx.x; j<1024; j+=THREADS){
    uint32_t hv = h[j];
    if (j<b3 && hv) acc += (float)hv * sigmoidf_fast(key2f(keybase | (uint32_t)j));
  }
  #pragma unroll
  for (int o=32;o>0;o>>=1) acc += __shfl_down(acc,o);
  __shared__ float rs[4];
  int wave=threadIdx.x>>6, lane=threadIdx.x&63;
  if(lane==0) rs[wave]=acc;
  __syncthreads();
  if (threadIdx.x==0){
    float v3 = sigmoidf_fast(key2f(keybase | (uint32_t)b3));
    sc->Ssm[s] = sc->Slow[s] + rs[0]+rs[1]+rs[2]+rs[3] + (float)r3 * v3;
  }
}

// ---------------- final combine ------------------------------------------
__global__ void k_final(const Scal* __restrict__ sc, float* __restrict__ out){
  int b = threadIdx.x; // 64 threads = 1 wave
  float tp = (2.f*sc->Ssm[b] - sc->Stot[b] + (float)sc->ones[b]) * (1.0f/(float)NPS);
  #pragma unroll
  for (int o=32;o>0;o>>=1) tp += __shfl_down(tp,o);
  if (b==0){
    float bce  = sc->bce / (float)TOTELEM;
    float uni  = sc->psum + sc->tsum;
    float dice = 1.f - (2.f*sc->inter + 1e-6f)/(uni + 1e-6f);
    out[0] = 0.5f*bce + 1.0f*dice + 0.5f*tp;
  }
}

extern "C" void kernel_launch(void* const* d_in, const int* in_sizes, int n_in,
                              void* d_out, int out_size, void* d_ws, size_t ws_size,
                              hipStream_t stream){
  const float* x = (const float*)d_in[0];
  const float* t = (const float*)d_in[1];
  float* out = (float*)d_out;
  uint8_t* ws = (uint8_t*)d_ws;
  uint32_t* Hist = (uint32_t*)ws;
  Scal* sc = (Scal*)(ws + HIST_BYTES);

  hipMemsetAsync(ws, 0, HIST_BYTES + sizeof(Scal), stream);
  k_pass1<<<NBLOCKS, THREADS, 0, stream>>>(x, t, Hist, sc);
  k_scan1<<<BATCH, THREADS, 0, stream>>>(Hist, sc);     // also zeroes Hist
  k_pass2<<<NBLOCKS, THREADS, 0, stream>>>(x, Hist, sc);
  k_scan2<<<BATCH, THREADS, 0, stream>>>(Hist, sc);     // also zeroes Hist
  k_pass3<<<NBLOCKS, THREADS, 0, stream>>>(x, Hist, sc);
  k_scan3<<<BATCH, THREADS, 0, stream>>>(Hist, sc);
  k_final<<<1, 64, 0, stream>>>(sc, out);
}

// Round 3
// 108.894 us; speedup vs baseline: 1.7927x; 1.7927x over previous
//
#include <hip/hip_runtime.h>
#include <stdint.h>

#define BATCH 64
#define NPS (512*512)                 // 262144 elements per sample
#define THREADS 256
#define BPS 16                        // blocks per sample
#define NBLOCKS (BATCH*BPS)           // 1024 blocks = 4/CU
#define EPB (NPS/BPS)                 // 16384 elements per block
#define V4 (EPB/(THREADS*4))          // 16 float4 iterations per thread
#define NBINS 512                     // sigmoid-space bins

// ws layout: Cnt u32[64][512] | Ssum f32[64][512] | Scal
#define CNT_BYTES (BATCH*NBINS*sizeof(uint32_t))   // 128 KiB
#define SSUM_BYTES (BATCH*NBINS*sizeof(float))     // 128 KiB

struct Scal {
  float bce[BATCH];
  float ps[BATCH];     // per-sample sigma(p) = Stot
  float inter[BATCH];  // per-sample sigma(p*t)
  uint32_t ones[BATCH];
  float Ssm[BATCH];    // interpolated S_small
};

__device__ __forceinline__ float sigmoidf_fast(float x){
  float e = __expf(-fabsf(x));
  float r = 1.0f/(1.0f+e);
  return (x >= 0.0f) ? r : 1.0f - r;
}

// ---- single fused pass: BCE/Dice sums + per-sample sigmoid-space hist ----
__global__ __launch_bounds__(THREADS) void k_main(
    const float* __restrict__ x, const float* __restrict__ t,
    uint32_t* __restrict__ Cnt, float* __restrict__ Ssum, Scal* __restrict__ sc)
{
  int s = blockIdx.x / BPS;
  int chunk = blockIdx.x % BPS;
  __shared__ uint32_t hc[NBINS];
  __shared__ float    hs[NBINS];
  for (int i = threadIdx.x; i < NBINS; i += THREADS){ hc[i] = 0u; hs[i] = 0.f; }
  __syncthreads();

  size_t base = (size_t)s*NPS + (size_t)chunk*EPB;
  const float4* x4 = (const float4*)(x + base);
  const float4* t4 = (const float4*)(t + base);
  float bce=0.f, ps=0.f, inter=0.f; uint32_t on=0;

  #pragma unroll 4
  for (int it=0; it<V4; ++it){
    float4 xv = x4[it*THREADS + threadIdx.x];
    float4 tv = t4[it*THREADS + threadIdx.x];
    float xs[4]  = {xv.x, xv.y, xv.z, xv.w};
    float tts[4] = {tv.x, tv.y, tv.z, tv.w};
    #pragma unroll
    for (int j=0;j<4;j++){
      float xx = xs[j], tt = tts[j];
      float e = __expf(-fabsf(xx));
      bce += fmaxf(xx,0.f) - xx*tt + __logf(1.f+e);
      float r = 1.f/(1.f+e);
      float p = (xx>=0.f) ? r : 1.f-r;
      ps += p; inter += p*tt; on += (tt>0.5f)?1u:0u;
      int bin = (int)(p*(float)NBINS); bin = (bin>NBINS-1)?(NBINS-1):bin;
      atomicAdd(&hc[bin], 1u);
      atomicAdd(&hs[bin], p);
    }
  }

  // block reduce scalar sums
  #pragma unroll
  for (int o=32;o>0;o>>=1){
    bce += __shfl_down(bce,o); ps += __shfl_down(ps,o);
    inter += __shfl_down(inter,o); on += __shfl_down(on,o);
  }
  __shared__ float rb[4], rp[4], ri[4]; __shared__ uint32_t ro[4];
  int wave = threadIdx.x >> 6, lane = threadIdx.x & 63;
  if (lane==0){ rb[wave]=bce; rp[wave]=ps; ri[wave]=inter; ro[wave]=on; }
  __syncthreads();
  if (threadIdx.x==0){
    atomicAdd(&sc->bce[s],   rb[0]+rb[1]+rb[2]+rb[3]);
    atomicAdd(&sc->ps[s],    rp[0]+rp[1]+rp[2]+rp[3]);
    atomicAdd(&sc->inter[s], ri[0]+ri[1]+ri[2]+ri[3]);
    atomicAdd(&sc->ones[s],  ro[0]+ro[1]+ro[2]+ro[3]);
  }
  __syncthreads();
  // flush histogram (16-way contended per address)
  for (int i = threadIdx.x; i < NBINS; i += THREADS){
    uint32_t c = hc[i];
    if (c){ atomicAdd(&Cnt[s*NBINS+i], c); atomicAdd(&Ssum[s*NBINS+i], hs[i]); }
  }
}

// ---- per-sample: find threshold bin, interpolate S_small -----------------
__global__ __launch_bounds__(THREADS) void k_fin(
    const uint32_t* __restrict__ Cnt, const float* __restrict__ Ssum, Scal* __restrict__ sc)
{
  int s = blockIdx.x;
  uint32_t z = (uint32_t)NPS - sc->ones[s];
  if (z == 0u){ if (threadIdx.x==0) sc->Ssm[s] = 0.f; return; }

  __shared__ uint32_t h[NBINS]; __shared__ float g[NBINS];
  __shared__ uint32_t pre[THREADS];
  __shared__ int sB; __shared__ uint32_t sr;
  for (int i=threadIdx.x;i<NBINS;i+=THREADS){ h[i]=Cnt[s*NBINS+i]; g[i]=Ssum[s*NBINS+i]; }
  __syncthreads();

  uint32_t local = h[threadIdx.x*2] + h[threadIdx.x*2+1];
  pre[threadIdx.x]=local;
  __syncthreads();
  if (threadIdx.x==0){ uint32_t c=0; for(int i=0;i<THREADS;i++){uint32_t v=pre[i]; pre[i]=c; c+=v;} }
  __syncthreads();
  uint32_t before = pre[threadIdx.x];
  if (before < z && z <= before+local){
    uint32_t c = before;
    #pragma unroll
    for (int j=0;j<2;j++){
      uint32_t hv = h[threadIdx.x*2+j];
      if (z <= c+hv){ sB = threadIdx.x*2+j; sr = z-c; break; }
      c += hv;
    }
  }
  __syncthreads();
  int B = sB; uint32_t r = sr;

  float acc = 0.f;
  #pragma unroll
  for (int j=0;j<2;j++){
    int idx = threadIdx.x*2+j;
    if (idx < B) acc += g[idx];
  }
  #pragma unroll
  for (int o=32;o>0;o>>=1) acc += __shfl_down(acc,o);
  __shared__ float rs[4];
  int wave=threadIdx.x>>6, lane=threadIdx.x&63;
  if (lane==0) rs[wave]=acc;
  __syncthreads();
  if (threadIdx.x==0){
    float below = rs[0]+rs[1]+rs[2]+rs[3];
    // interpolate within threshold bin: r of h[B] elements, avg value g[B]/h[B]
    sc->Ssm[s] = below + ((float)r/(float)h[B]) * g[B];
  }
}

// ---- final combine (one wave) --------------------------------------------
__global__ void k_final(const Scal* __restrict__ sc, float* __restrict__ out){
  int b = threadIdx.x; // 64 lanes = 64 samples
  float Stot = sc->ps[b];
  float onef = (float)sc->ones[b];
  float tp   = (2.f*sc->Ssm[b] - Stot + onef) * (1.0f/(float)NPS);
  float bce  = sc->bce[b];
  float inter= sc->inter[b];
  float psum = Stot;
  #pragma unroll
  for (int o=32;o>0;o>>=1){
    tp   += __shfl_down(tp,o);   bce  += __shfl_down(bce,o);
    psum += __shfl_down(psum,o); inter+= __shfl_down(inter,o);
    onef += __shfl_down(onef,o);
  }
  if (b==0){
    float mbce = bce / ((float)BATCH*(float)NPS);
    float dice = 1.f - (2.f*inter + 1e-6f)/(psum + onef + 1e-6f);
    out[0] = 0.5f*mbce + 1.0f*dice + 0.5f*tp;
  }
}

extern "C" void kernel_launch(void* const* d_in, const int* in_sizes, int n_in,
                              void* d_out, int out_size, void* d_ws, size_t ws_size,
                              hipStream_t stream){
  const float* x = (const float*)d_in[0];
  const float* t = (const float*)d_in[1];
  float* out = (float*)d_out;
  uint8_t* ws = (uint8_t*)d_ws;
  uint32_t* Cnt = (uint32_t*)ws;
  float* Ssum = (float*)(ws + CNT_BYTES);
  Scal* sc = (Scal*)(ws + CNT_BYTES + SSUM_BYTES);

  hipMemsetAsync(ws, 0, CNT_BYTES + SSUM_BYTES + sizeof(Scal), stream);
  k_main<<<NBLOCKS, THREADS, 0, stream>>>(x, t, Cnt, Ssum, sc);
  k_fin<<<BATCH, THREADS, 0, stream>>>(Cnt, Ssum, sc);
  k_final<<<1, 64, 0, stream>>>(sc, out);
}

// Round 4
// 44.812 us; speedup vs baseline: 4.3565x; 2.4300x over previous
//
#include <hip/hip_runtime.h>
#include <stdint.h>

#define BATCH 64
#define NPS (512*512)                 // 262144 elements per sample
#define THREADS 256
#define BPS 32                        // blocks per sample
#define NBLOCKS (BATCH*BPS)           // 2048 blocks = 8/CU (full residency)
#define EPB (NPS/BPS)                 // 8192 elements per block
#define V4 (EPB/(THREADS*4))          // 8 float4 iterations per thread
#define NBINS 512                     // sigmoid-space bins

// ws layout: Cnt2 u32[NBLOCKS][NBINS] (4 MiB) | Scal
#define CNT2_BYTES (NBLOCKS*NBINS*sizeof(uint32_t))

struct Scal {
  float bce[BATCH];
  float ps[BATCH];     // per-sample sigma(p)
  float inter[BATCH];  // per-sample sigma(p*t)
  uint32_t ones[BATCH];
  float Ssm[BATCH];    // approx S_small
};

// ---- fused pass: BCE/Dice sums + per-sample sigmoid-space count hist ----
__global__ __launch_bounds__(THREADS) void k_main(
    const float* __restrict__ x, const float* __restrict__ t,
    uint32_t* __restrict__ Cnt2, Scal* __restrict__ sc)
{
  int s = blockIdx.x / BPS;
  int chunk = blockIdx.x % BPS;
  __shared__ uint32_t hc[NBINS];
  for (int i = threadIdx.x; i < NBINS; i += THREADS) hc[i] = 0u;
  __syncthreads();

  size_t base = (size_t)s*NPS + (size_t)chunk*EPB;
  const float4* x4 = (const float4*)(x + base);
  const float4* t4 = (const float4*)(t + base);
  float bce=0.f, ps=0.f, inter=0.f; uint32_t on=0;

  #pragma unroll
  for (int it=0; it<V4; ++it){
    float4 xv = x4[it*THREADS + threadIdx.x];
    float4 tv = t4[it*THREADS + threadIdx.x];
    float xs[4]  = {xv.x, xv.y, xv.z, xv.w};
    float tts[4] = {tv.x, tv.y, tv.z, tv.w};
    #pragma unroll
    for (int j=0;j<4;j++){
      float xx = xs[j], tt = tts[j];
      float e = __expf(-fabsf(xx));
      float u = 1.f + e;
      bce += fmaxf(xx,0.f) - xx*tt + __logf(u);
      float r = 1.f/u;                    // sigmoid(|x|)
      float p = (xx>=0.f) ? r : 1.f-r;
      ps += p; inter += p*tt; on += (tt>0.5f)?1u:0u;
      int bin = (int)(p*(float)NBINS); bin = (bin>NBINS-1)?(NBINS-1):bin;
      atomicAdd(&hc[bin], 1u);
    }
  }

  // block-reduce scalar sums
  #pragma unroll
  for (int o=32;o>0;o>>=1){
    bce += __shfl_down(bce,o); ps += __shfl_down(ps,o);
    inter += __shfl_down(inter,o); on += __shfl_down(on,o);
  }
  __shared__ float rb[4], rp[4], ri[4]; __shared__ uint32_t ro[4];
  int wave = threadIdx.x >> 6, lane = threadIdx.x & 63;
  if (lane==0){ rb[wave]=bce; rp[wave]=ps; ri[wave]=inter; ro[wave]=on; }
  __syncthreads();
  if (threadIdx.x==0){
    atomicAdd(&sc->bce[s],   rb[0]+rb[1]+rb[2]+rb[3]);
    atomicAdd(&sc->ps[s],    rp[0]+rp[1]+rp[2]+rp[3]);
    atomicAdd(&sc->inter[s], ri[0]+ri[1]+ri[2]+ri[3]);
    atomicAdd(&sc->ones[s],  ro[0]+ro[1]+ro[2]+ro[3]);
  }
  __syncthreads();
  // contention-free flush: plain coalesced stores to private slice
  uint32_t* dst = Cnt2 + (size_t)blockIdx.x * NBINS;
  for (int i = threadIdx.x; i < NBINS; i += THREADS) dst[i] = hc[i];
}

// ---- per-sample: sum slices, find threshold bin, approx S_small ---------
__global__ __launch_bounds__(THREADS) void k_fin(
    const uint32_t* __restrict__ Cnt2, Scal* __restrict__ sc)
{
  int s = blockIdx.x;
  uint32_t z = (uint32_t)NPS - sc->ones[s];
  if (z == 0u){ if (threadIdx.x==0) sc->Ssm[s] = 0.f; return; }

  __shared__ uint32_t h[NBINS];
  __shared__ uint32_t pre[THREADS];
  __shared__ int sB; __shared__ uint32_t sr;

  // sum the 32 per-block slices: thread owns bins {2t, 2t+1}
  uint32_t h0 = 0u, h1 = 0u;
  const uint32_t* basep = Cnt2 + (size_t)s * BPS * NBINS + 2u*threadIdx.x;
  #pragma unroll 8
  for (int c = 0; c < BPS; ++c){
    uint2 v = *(const uint2*)(basep + (size_t)c * NBINS);
    h0 += v.x; h1 += v.y;
  }
  h[2*threadIdx.x] = h0; h[2*threadIdx.x+1] = h1;
  uint32_t local = h0 + h1;
  pre[threadIdx.x] = local;
  __syncthreads();
  if (threadIdx.x==0){ uint32_t c=0; for(int i=0;i<THREADS;i++){uint32_t v=pre[i]; pre[i]=c; c+=v;} }
  __syncthreads();
  uint32_t before = pre[threadIdx.x];
  if (before < z && z <= before+local){
    if (z <= before + h0){ sB = 2*threadIdx.x;   sr = z - before; }
    else                 { sB = 2*threadIdx.x+1; sr = z - before - h0; }
  }
  __syncthreads();
  int B = sB; uint32_t r = sr;

  // S_small ~= sum_{b<B} h[b]*center(b) + r*center(B)
  float acc = 0.f;
  if (2*threadIdx.x   < B) acc += (float)h0 * ((float)(2*threadIdx.x)  +0.5f);
  if (2*threadIdx.x+1 < B) acc += (float)h1 * ((float)(2*threadIdx.x+1)+0.5f);
  #pragma unroll
  for (int o=32;o>0;o>>=1) acc += __shfl_down(acc,o);
  __shared__ float rs[4];
  int wave=threadIdx.x>>6, lane=threadIdx.x&63;
  if (lane==0) rs[wave]=acc;
  __syncthreads();
  if (threadIdx.x==0){
    float below = rs[0]+rs[1]+rs[2]+rs[3] + (float)r * ((float)B + 0.5f);
    sc->Ssm[s] = below * (1.0f/(float)NBINS);
  }
}

// ---- final combine (one wave) --------------------------------------------
__global__ void k_final(const Scal* __restrict__ sc, float* __restrict__ out){
  int b = threadIdx.x; // 64 lanes = 64 samples
  float Stot = sc->ps[b];
  float onef = (float)sc->ones[b];
  float tp   = (2.f*sc->Ssm[b] - Stot + onef) * (1.0f/(float)NPS);
  float bce  = sc->bce[b];
  float inter= sc->inter[b];
  float psum = Stot;
  #pragma unroll
  for (int o=32;o>0;o>>=1){
    tp   += __shfl_down(tp,o);   bce  += __shfl_down(bce,o);
    psum += __shfl_down(psum,o); inter+= __shfl_down(inter,o);
    onef += __shfl_down(onef,o);
  }
  if (b==0){
    float mbce = bce / ((float)BATCH*(float)NPS);
    float dice = 1.f - (2.f*inter + 1e-6f)/(psum + onef + 1e-6f);
    out[0] = 0.5f*mbce + 1.0f*dice + 0.5f*tp;
  }
}

extern "C" void kernel_launch(void* const* d_in, const int* in_sizes, int n_in,
                              void* d_out, int out_size, void* d_ws, size_t ws_size,
                              hipStream_t stream){
  const float* x = (const float*)d_in[0];
  const float* t = (const float*)d_in[1];
  float* out = (float*)d_out;
  uint8_t* ws = (uint8_t*)d_ws;
  uint32_t* Cnt2 = (uint32_t*)ws;
  Scal* sc = (Scal*)(ws + CNT2_BYTES);

  hipMemsetAsync(sc, 0, sizeof(Scal), stream);   // Cnt2 fully overwritten, no memset
  k_main<<<NBLOCKS, THREADS, 0, stream>>>(x, t, Cnt2, sc);
  k_fin<<<BATCH, THREADS, 0, stream>>>(Cnt2, sc);
  k_final<<<1, 64, 0, stream>>>(sc, out);
}